// Round 9
// baseline (182.088 us; speedup 1.0000x reference)
//
#include <hip/hip_runtime.h>
#include <hip/hip_bf16.h>

// B=8, E=64, CIN=C=PRE=128. fp32 I/O; bf16 MFMA everywhere GEMM-shaped.
// R9: 3 blocks/CU for attnc (LDS 51KB via aux aliasing) and conv2 (sSc aliased
// into sB2); path_mat/p_bias register-prefetched above the first barrier.

typedef unsigned short u16;
typedef unsigned int u32;
typedef short s16x8 __attribute__((ext_vector_type(8)));
typedef float f32x4 __attribute__((ext_vector_type(4)));

__device__ __forceinline__ float b2f(u16 u) { return __uint_as_float(((u32)u) << 16); }
__device__ __forceinline__ u16 f2b(float f) {
    u32 x = __float_as_uint(f);
    u32 r = (x + 0x7fffu + ((x >> 16) & 1u)) >> 16;   // RNE
    return (u16)r;
}
__device__ __forceinline__ float lk(float v) { return v >= 0.f ? v : 0.1f * v; }
__device__ __forceinline__ s16x8 cvt8(const float* p) {
    float4 a = ((const float4*)p)[0], c = ((const float4*)p)[1];
    s16x8 r;
    r[0] = (short)f2b(a.x); r[1] = (short)f2b(a.y); r[2] = (short)f2b(a.z); r[3] = (short)f2b(a.w);
    r[4] = (short)f2b(c.x); r[5] = (short)f2b(c.y); r[6] = (short)f2b(c.z); r[7] = (short)f2b(c.w);
    return r;
}

// ---------------- K1: merged prep.
// [0,768): weight frags; [768,800): front GEMMs; [800,1312): pre->preT.
__global__ __launch_bounds__(256) void k_prep(const float* __restrict__ w1, const float* __restrict__ w2,
                                              u16* __restrict__ wA1, u16* __restrict__ wA2,
                                              const float* __restrict__ x, const float* __restrict__ y,
                                              const float* __restrict__ xc1, const float* __restrict__ yc1,
                                              const float* __restrict__ xc2w, const float* __restrict__ xc2b,
                                              const float* __restrict__ yc2w, const float* __restrict__ yc2b,
                                              const float* __restrict__ xlw, const float* __restrict__ ylw,
                                              u16* __restrict__ xfb, u16* __restrict__ yfb,
                                              float* __restrict__ xfT, float* __restrict__ yfT,
                                              u16* __restrict__ xlT, u16* __restrict__ ylT,
                                              float* __restrict__ Xs, float* __restrict__ Yo,
                                              const float* __restrict__ pre, u16* __restrict__ preT) {
    int bid = blockIdx.x;
    int t = threadIdx.x;
    if (bid < 768) {
        int idx = bid * 256 + t;
        if (idx < 49152) {
            int e = idx & 7, lane = (idx >> 3) & 63, mtg = (idx >> 9) & 7, kc = idx >> 12;
            int o = mtg * 16 + (lane & 15), c = kc * 32 + ((lane >> 4) << 3) + e;
            wA1[idx] = f2b(w1[o * 384 + c]);
        } else {
            int id2 = idx - 49152;
            if (id2 < 147456) {
                int e = id2 & 7, lane = (id2 >> 3) & 63, mtg = (id2 >> 9) & 7;
                int kc = (id2 >> 12) & 3, tap = id2 >> 14;
                int o = mtg * 16 + (lane & 15), c = kc * 32 + ((lane >> 4) << 3) + e;
                wA2[id2] = f2b(w2[(o * 128 + c) * 9 + tap]);
            }
        }
        return;
    }
    if (bid < 800) {
        int r = bid - 768;
        int b = r >> 2, g4 = r & 3;
        int lane = t & 63, w = t >> 6, l15 = lane & 15, q4 = lane >> 4;
        __shared__ u16 sT[64][136];
        const float* src = (g4 == 0 || g4 == 2) ? x : y;
        const float* wptr = (g4 == 0) ? xc1 : (g4 == 1) ? yc1 : (g4 == 2) ? xlw : ylw;
        {
            int i = t >> 1, m0 = (t & 1) * 32;
            const float4* ps = (const float4*)(src + (b * 128 + i) * 64 + m0);
#pragma unroll
            for (int q = 0; q < 8; ++q) {
                float4 v = ps[q];
                int m = m0 + q * 4;
                sT[m + 0][i] = f2b(v.x); sT[m + 1][i] = f2b(v.y);
                sT[m + 2][i] = f2b(v.z); sT[m + 3][i] = f2b(v.w);
            }
        }
        __syncthreads();
        int m = w * 16 + l15;
        f32x4 acc[8];
#pragma unroll
        for (int mt = 0; mt < 8; ++mt) acc[mt] = (f32x4)(0.f);
#pragma unroll
        for (int kt = 0; kt < 4; ++kt) {
            s16x8 bfr = *(const s16x8*)&sT[m][kt * 32 + q4 * 8];
#pragma unroll
            for (int mt = 0; mt < 8; ++mt) {
                s16x8 af = cvt8(wptr + (mt * 16 + l15) * 128 + kt * 32 + q4 * 8);
                acc[mt] = __builtin_amdgcn_mfma_f32_16x16x32_bf16(af, bfr, acc[mt], 0, 0, 0);
            }
        }
        if (g4 == 0 || g4 == 1) {
            u16* fb = (g4 == 0) ? xfb : yfb;
            float* fT = (g4 == 0) ? xfT : yfT;
            const float* c2w = (g4 == 0) ? xc2w : yc2w;
            const float* c2b = (g4 == 0) ? xc2b : yc2b;
            float* dvec = (g4 == 0) ? Xs : Yo;
            float sp = 0.f;
#pragma unroll
            for (int mt = 0; mt < 8; ++mt) {
                int c0 = mt * 16 + q4 * 4;
                f32x4 a = acc[mt];
                fb[(b * 128 + c0 + 0) * 64 + m] = f2b(a[0]);
                fb[(b * 128 + c0 + 1) * 64 + m] = f2b(a[1]);
                fb[(b * 128 + c0 + 2) * 64 + m] = f2b(a[2]);
                fb[(b * 128 + c0 + 3) * 64 + m] = f2b(a[3]);
                *(float4*)(fT + (b * 64 + m) * 128 + c0) = make_float4(a[0], a[1], a[2], a[3]);
                float4 wv = *(const float4*)(c2w + c0);
                sp += wv.x * a[0] + wv.y * a[1] + wv.z * a[2] + wv.w * a[3];
            }
            sp += __shfl_xor(sp, 16);
            sp += __shfl_xor(sp, 32);
            if (q4 == 0) dvec[b * 64 + m] = sp + c2b[0];
        } else {
            u16* lT = (g4 == 2) ? xlT : ylT;
#pragma unroll
            for (int mt = 0; mt < 8; ++mt) {
                int i0 = mt * 16 + q4 * 4;
                f32x4 a = acc[mt];
                lT[(b * 128 + i0 + 0) * 64 + m] = f2b(a[0]);
                lT[(b * 128 + i0 + 1) * 64 + m] = f2b(a[1]);
                lT[(b * 128 + i0 + 2) * 64 + m] = f2b(a[2]);
                lT[(b * 128 + i0 + 3) * 64 + m] = f2b(a[3]);
            }
        }
        return;
    }
    {
        int r = bid - 800;
        int b = r >> 6, i = r & 63;
        int j = t & 63, pg = t >> 6;
#pragma unroll
        for (int oc = 0; oc < 4; ++oc) {
            int p0 = pg * 32 + oc * 8;
            s16x8 v;
#pragma unroll
            for (int k = 0; k < 8; ++k)
                v[k] = (short)f2b(pre[((b * 128 + p0 + k) * 64 + i) * 64 + j]);
            *(s16x8*)(preT + ((b * 64 + i) * 64 + j) * 128 + p0) = v;
        }
    }
}

// ---------------- K2: fused attention + conv1, exp-once, register-prefetched inputs.
// LDS 51 KB -> 3 blocks/CU.
__global__ __launch_bounds__(256) void k_attnc(const float* __restrict__ Xs, const float* __restrict__ Yo,
                                               const u16* __restrict__ xfb, const u16* __restrict__ yfb,
                                               const float* __restrict__ xfT, const float* __restrict__ yfT,
                                               const int* __restrict__ path_mat, const float* __restrict__ p_bias,
                                               const float* __restrict__ ptab, const float* __restrict__ pconv,
                                               const u16* __restrict__ preT, const u16* __restrict__ wA1,
                                               const float* __restrict__ b1, u16* __restrict__ hT) {
    int b = blockIdx.x >> 6, e = blockIdx.x & 63;
    int t = threadIdx.x;
    int lane = t & 63, w = t >> 6;
    // smem0: sAf f32[64][68] (17408B) | aux (sRed 256f, sPdot 32f, sXv 64f, sYv 64f)
    // all aliased by sMen u16[64][264] (33792B) once GEMM phase starts.
    __shared__ __align__(16) char smem0[64 * 264 * 2];
    float* sAf = (float*)smem0;
    u16* sMen = (u16*)smem0;
    float* sRed = (float*)(smem0 + 17408);
    float* sPdot = sRed + 256;
    float* sXv = sPdot + 32;
    float* sYv = sXv + 64;
    __shared__ u16 Abf[64][72];
    __shared__ u16 E2bf[64][72];

    int tr = t >> 2, tq = t & 3, tn0 = tq * 16;

    // register prefetch: path_mat/p_bias rows (independent of LDS, issued first)
    int4 pmr[4]; float4 pbr[4];
    {
        int base = (((b * 64 + e) * 64 + tr) * 64 + tn0);
        const int4* pm4 = (const int4*)(path_mat + base);
        const float4* pb4 = (const float4*)(p_bias + base);
#pragma unroll
        for (int q2 = 0; q2 < 4; ++q2) { pmr[q2] = pm4[q2]; pbr[q2] = pb4[q2]; }
    }

    if (t < 20) {
        float s = 0.f;
        for (int d = 0; d < 32; ++d) s += ptab[t * 32 + d] * pconv[d];
        sPdot[t] = lk(s);
    } else if (t >= 64 && t < 128) {
        sXv[t - 64] = Xs[b * 64 + t - 64];
    } else if (t >= 128 && t < 192) {
        sYv[t - 128] = Yo[b * 64 + t - 128];
    }
    __syncthreads();

    // P1: local scores + inline row max
    {
        float yom = sYv[tr];
        float mx = -1e30f;
#pragma unroll
        for (int q2 = 0; q2 < 4; ++q2) {
            int4 pm = pmr[q2]; float4 pb = pbr[q2];
            int n = tn0 + q2 * 4;
            float4 v;
            v.x = lk(sXv[n + 0] + yom) + sPdot[pm.x] + pb.x;
            v.y = lk(sXv[n + 1] + yom) + sPdot[pm.y] + pb.y;
            v.z = lk(sXv[n + 2] + yom) + sPdot[pm.z] + pb.z;
            v.w = lk(sXv[n + 3] + yom) + sPdot[pm.w] + pb.w;
            *(float4*)&sAf[tr * 68 + n] = v;
            mx = fmaxf(mx, fmaxf(fmaxf(v.x, v.y), fmaxf(v.z, v.w)));
        }
        mx = fmaxf(mx, __shfl_xor(mx, 1));
        mx = fmaxf(mx, __shfl_xor(mx, 2));
        if (tq == 0) sRed[tr] = mx;
    }
    __syncthreads();

    // P2: wave0 computes global M and er2; all rows exponentiate once + rowsum
    if (t < 64) {
        float rm = sRed[t];
        float M = rm;
#pragma unroll
        for (int off = 1; off < 64; off <<= 1) M = fmaxf(M, __shfl_xor(M, off));
        sRed[128 + t] = __expf(rm - M);
    }
    {
        float rmax = sRed[tr];
        float4* rp = (float4*)&sAf[tr * 68 + tn0];
        float s = 0.f;
#pragma unroll
        for (int q2 = 0; q2 < 4; ++q2) {
            float4 v = rp[q2];
            float4 ev;
            ev.x = __expf(v.x - rmax); ev.y = __expf(v.y - rmax);
            ev.z = __expf(v.z - rmax); ev.w = __expf(v.w - rmax);
            s += ev.x + ev.y + ev.z + ev.w;
            rp[q2] = ev;
        }
        s += __shfl_xor(s, 1);
        s += __shfl_xor(s, 2);
        if (tq == 0) sRed[64 + tr] = 1.f / s;
    }
    __syncthreads();

    // P2c: col sums of E*er2
    {
        float cs = 0.f;
#pragma unroll
        for (int k = 0; k < 16; ++k) {
            int mm = tn0 + k;
            cs += sAf[mm * 68 + tr] * sRed[128 + mm];
        }
        cs += __shfl_xor(cs, 1);
        cs += __shfl_xor(cs, 2);
        if (tq == 0) sRed[192 + tr] = 1.f / cs;
    }
    __syncthreads();

    // P3: pack Abf / E2bf — no exps
    {
        float rinv = sRed[64 + tr];
        const float4* rp = (const float4*)&sAf[tr * 68 + tn0];
#pragma unroll
        for (int g2 = 0; g2 < 2; ++g2) {
            float4 v0 = rp[g2 * 2], v1 = rp[g2 * 2 + 1];
            s16x8 pk;
            pk[0] = (short)f2b(v0.x * rinv); pk[1] = (short)f2b(v0.y * rinv);
            pk[2] = (short)f2b(v0.z * rinv); pk[3] = (short)f2b(v0.w * rinv);
            pk[4] = (short)f2b(v1.x * rinv); pk[5] = (short)f2b(v1.y * rinv);
            pk[6] = (short)f2b(v1.z * rinv); pk[7] = (short)f2b(v1.w * rinv);
            *(s16x8*)&Abf[tr][tn0 + g2 * 8] = pk;
        }
    }
    {
        float cinv = sRed[192 + tr];
#pragma unroll
        for (int g2 = 0; g2 < 2; ++g2) {
            s16x8 pk;
#pragma unroll
            for (int k = 0; k < 8; ++k) {
                int mm = tn0 + g2 * 8 + k;
                pk[k] = (short)f2b(sAf[mm * 68 + tr] * sRed[128 + mm] * cinv);
            }
            *(s16x8*)&E2bf[tr][tn0 + g2 * 8] = pk;
        }
    }
    __syncthreads();   // sAf + aux dead; sMen may be written now

    int l15 = lane & 15, q4 = lane >> 4;
    // GEMM1: xret[c][m] -> sMen[m][c], c<128
    {
        f32x4 acc[2][4];
#pragma unroll
        for (int ci = 0; ci < 2; ++ci)
#pragma unroll
            for (int mt = 0; mt < 4; ++mt) acc[ci][mt] = (f32x4)(0.f);
#pragma unroll
        for (int kt = 0; kt < 2; ++kt) {
            s16x8 afr[2];
#pragma unroll
            for (int ci = 0; ci < 2; ++ci) {
                int c = (2 * w + ci) * 16 + l15;
                afr[ci] = *(const s16x8*)(yfb + (b * 128 + c) * 64 + kt * 32 + q4 * 8);
            }
            s16x8 bfr[4];
#pragma unroll
            for (int mt = 0; mt < 4; ++mt)
                bfr[mt] = *(const s16x8*)&Abf[mt * 16 + l15][kt * 32 + q4 * 8];
#pragma unroll
            for (int ci = 0; ci < 2; ++ci)
#pragma unroll
                for (int mt = 0; mt < 4; ++mt)
                    acc[ci][mt] = __builtin_amdgcn_mfma_f32_16x16x32_bf16(afr[ci], bfr[mt], acc[ci][mt], 0, 0, 0);
        }
#pragma unroll
        for (int ci = 0; ci < 2; ++ci) {
            int c0 = (2 * w + ci) * 16 + q4 * 4;
#pragma unroll
            for (int mt = 0; mt < 4; ++mt) {
                int m = mt * 16 + l15;
                float4 res = *(const float4*)(xfT + (b * 64 + m) * 128 + c0);
                f32x4 a = acc[ci][mt];
                u32 lo = (u32)f2b(lk(a[0] + res.x)) | ((u32)f2b(lk(a[1] + res.y)) << 16);
                u32 hi = (u32)f2b(lk(a[2] + res.z)) | ((u32)f2b(lk(a[3] + res.w)) << 16);
                *(uint2*)&sMen[m * 264 + c0] = make_uint2(lo, hi);
            }
        }
    }
    // GEMM2: yret[c][n] -> sMen[n][128+c]
    {
        f32x4 acc[2][4];
#pragma unroll
        for (int ci = 0; ci < 2; ++ci)
#pragma unroll
            for (int nt = 0; nt < 4; ++nt) acc[ci][nt] = (f32x4)(0.f);
#pragma unroll
        for (int kt = 0; kt < 2; ++kt) {
            s16x8 afr[2];
#pragma unroll
            for (int ci = 0; ci < 2; ++ci) {
                int c = (2 * w + ci) * 16 + l15;
                afr[ci] = *(const s16x8*)(xfb + (b * 128 + c) * 64 + kt * 32 + q4 * 8);
            }
            s16x8 bfr[4];
#pragma unroll
            for (int nt = 0; nt < 4; ++nt)
                bfr[nt] = *(const s16x8*)&E2bf[nt * 16 + l15][kt * 32 + q4 * 8];
#pragma unroll
            for (int ci = 0; ci < 2; ++ci)
#pragma unroll
                for (int nt = 0; nt < 4; ++nt)
                    acc[ci][nt] = __builtin_amdgcn_mfma_f32_16x16x32_bf16(afr[ci], bfr[nt], acc[ci][nt], 0, 0, 0);
        }
#pragma unroll
        for (int ci = 0; ci < 2; ++ci) {
            int c0 = (2 * w + ci) * 16 + q4 * 4;
#pragma unroll
            for (int nt = 0; nt < 4; ++nt) {
                int n = nt * 16 + l15;
                float4 res = *(const float4*)(yfT + (b * 64 + n) * 128 + c0);
                f32x4 a = acc[ci][nt];
                u32 lo = (u32)f2b(lk(a[0] + res.x)) | ((u32)f2b(lk(a[1] + res.y)) << 16);
                u32 hi = (u32)f2b(lk(a[2] + res.z)) | ((u32)f2b(lk(a[3] + res.w)) << 16);
                *(uint2*)&sMen[n * 264 + 128 + c0] = make_uint2(lo, hi);
            }
        }
    }
    __syncthreads();

    // conv1 for output row i=e: B from sMen (kc<8) / preT (kc>=8)
    {
        int wm = w & 1, wn = w >> 1;
        f32x4 acc[4][2];
#pragma unroll
        for (int mt = 0; mt < 4; ++mt)
#pragma unroll
            for (int nt = 0; nt < 2; ++nt) acc[mt][nt] = (f32x4)(0.f);
        const u16* prow = preT + (b * 64 + e) * 64 * 128;
        for (int kc = 0; kc < 12; ++kc) {
            s16x8 af[4];
#pragma unroll
            for (int mt = 0; mt < 4; ++mt)
                af[mt] = *(const s16x8*)(wA1 + (((kc * 8 + wm * 4 + mt) * 64 + lane) << 3));
            s16x8 bf[2];
#pragma unroll
            for (int nt = 0; nt < 2; ++nt) {
                int j = (wn * 2 + nt) * 16 + l15;
                bf[nt] = (kc < 8) ? *(const s16x8*)&sMen[j * 264 + kc * 32 + q4 * 8]
                                  : *(const s16x8*)(prow + j * 128 + (kc - 8) * 32 + q4 * 8);
            }
#pragma unroll
            for (int mt = 0; mt < 4; ++mt)
#pragma unroll
                for (int nt = 0; nt < 2; ++nt)
                    acc[mt][nt] = __builtin_amdgcn_mfma_f32_16x16x32_bf16(af[mt], bf[nt], acc[mt][nt], 0, 0, 0);
        }
#pragma unroll
        for (int mt = 0; mt < 4; ++mt) {
            int o0 = (wm * 4 + mt) * 16 + q4 * 4;
            float4 bb = *(const float4*)(b1 + o0);
#pragma unroll
            for (int nt = 0; nt < 2; ++nt) {
                int j = (wn * 2 + nt) * 16 + l15;
                f32x4 a = acc[mt][nt];
                u32 lo = (u32)f2b(lk(a[0] + bb.x)) | ((u32)f2b(lk(a[1] + bb.y)) << 16);
                u32 hi = (u32)f2b(lk(a[2] + bb.z)) | ((u32)f2b(lk(a[3] + bb.w)) << 16);
                *(uint2*)(hT + ((b * 64 + e) * 64 + j) * 128 + o0) = make_uint2(lo, hi);
            }
        }
    }
}

// ---------------- K3: conv2 (3x3 SAME) MFMA, LDS-staged halo; sSc aliased into sB2
__global__ __launch_bounds__(256) void k_conv2(const u16* __restrict__ hT, const u16* __restrict__ wA2,
                                               const float* __restrict__ b2, const float* __restrict__ score_w,
                                               const float* __restrict__ Xs, const float* __restrict__ Yo,
                                               const float* __restrict__ etab, const float* __restrict__ econv,
                                               const int* __restrict__ edge_mat, const float* __restrict__ m_bias,
                                               float* __restrict__ m2r, float* __restrict__ g) {
    int b = blockIdx.x >> 6, i = blockIdx.x & 63;
    int t = threadIdx.x;
    int lane = t & 63, w = t >> 6, wm = w & 1, wn = w >> 1;
    int l15 = lane & 15, q4 = lane >> 4;
    __shared__ u16 sB2[3][66][136];
    float* sSc = (float*)&sB2[0][0][0];   // aliased: sB2 dead by the time sSc is written
    __shared__ float sEd[16];

    if (t >= 240 && t < 250) {
        int et = t - 240;
        float s = 0.f;
        for (int d = 0; d < 32; ++d) s += etab[et * 32 + d] * econv[d];
        sEd[et] = lk(s);
    }
#pragma unroll
    for (int q = 0; q < 2; ++q) {
        int u = q * 256 + t;
        if (u < 384) {
            int r = u >> 7, rem = u & 127, hcol = rem >> 6, c2 = rem & 63;
            *(u32*)&sB2[r][hcol ? 65 : 0][c2 * 2] = 0u;
        }
    }
#pragma unroll
    for (int it = 0; it < 12; ++it) {
        int u = it * 256 + t;
        int cg = u & 15, j = (u >> 4) & 63, r = u >> 10;
        int ir = i - 1 + r;
        int4 v = make_int4(0, 0, 0, 0);
        if (ir >= 0 && ir < 64)
            v = *(const int4*)(hT + ((b * 64 + ir) * 64 + j) * 128 + cg * 8);
        *(int4*)&sB2[r][j + 1][cg * 8] = v;
    }
    __syncthreads();

    f32x4 acc[4][2];
#pragma unroll
    for (int mt = 0; mt < 4; ++mt)
#pragma unroll
        for (int nt = 0; nt < 2; ++nt) acc[mt][nt] = (f32x4)(0.f);

    for (int kc = 0; kc < 4; ++kc) {
#pragma unroll
        for (int tap = 0; tap < 9; ++tap) {
            int di = tap / 3, dj = tap % 3;
            s16x8 af[4];
#pragma unroll
            for (int mt = 0; mt < 4; ++mt)
                af[mt] = *(const s16x8*)(wA2 + ((((tap * 4 + kc) * 8 + wm * 4 + mt) * 64 + lane) << 3));
#pragma unroll
            for (int nt = 0; nt < 2; ++nt) {
                int jin = wn * 32 + nt * 16 + l15 + dj;
                s16x8 bf = *(const s16x8*)(&sB2[di][jin][kc * 32 + q4 * 8]);
#pragma unroll
                for (int mt = 0; mt < 4; ++mt)
                    acc[mt][nt] = __builtin_amdgcn_mfma_f32_16x16x32_bf16(af[mt], bf, acc[mt][nt], 0, 0, 0);
            }
        }
    }

    float part[2] = {0.f, 0.f};
#pragma unroll
    for (int mt = 0; mt < 4; ++mt) {
        int o0 = wm * 64 + mt * 16 + q4 * 4;
        float4 bb = *(const float4*)(b2 + o0);
        float4 sw = *(const float4*)(score_w + o0);
#pragma unroll
        for (int nt = 0; nt < 2; ++nt) {
            int j = wn * 32 + nt * 16 + l15;
            f32x4 a = acc[mt][nt];
            float v0 = lk(a[0] + bb.x), v1 = lk(a[1] + bb.y);
            float v2 = lk(a[2] + bb.z), v3 = lk(a[3] + bb.w);
            float* dst = m2r + ((b * 128 + o0) * 64 + i) * 64 + j;
            dst[0] = v0; dst[4096] = v1; dst[8192] = v2; dst[12288] = v3;
            part[nt] += sw.x * v0 + sw.y * v1 + sw.z * v2 + sw.w * v3;
        }
    }
    __syncthreads();   // all sB2 reads complete before sSc overwrites it
#pragma unroll
    for (int nt = 0; nt < 2; ++nt) {
        float p = part[nt];
        p += __shfl_xor(p, 16);
        p += __shfl_xor(p, 32);
        if (q4 == 0) sSc[wm * 64 + wn * 32 + nt * 16 + l15] = p;
    }
    __syncthreads();
    if (t < 64) {
        float s = sSc[t] + sSc[64 + t];
        int gi = (b * 64 + i) * 64 + t;
        float L = lk(Xs[b * 64 + t] + Yo[b * 64 + i]);
        g[gi] = L + sEd[edge_mat[gi]] + m_bias[gi] + lk(s);
    }
}

// ---------------- K4: final softmax+GEMM+residual, exp-once, block=(b, direction)
__global__ __launch_bounds__(256) void k_gout(const float* __restrict__ g,
                                              const u16* __restrict__ xlT, const u16* __restrict__ ylT,
                                              const float* __restrict__ x, const float* __restrict__ y,
                                              float* __restrict__ out) {
    int b = blockIdx.x >> 1, which = blockIdx.x & 1;
    int t = threadIdx.x;
    int lane = t & 63, w = t >> 6, l15 = lane & 15, q4 = lane >> 4;
    __shared__ float sG[64][68];
    __shared__ u16 Gbf[64][72];
    __shared__ float sRed[256];

    int tr = t >> 2, tq = t & 3, tn0 = tq * 16;

    {
        const float4* gp = (const float4*)(g + b * 4096 + tr * 64 + tn0);
        float mx = -1e30f;
#pragma unroll
        for (int q2 = 0; q2 < 4; ++q2) {
            float4 v = gp[q2];
            *(float4*)&sG[tr][tn0 + q2 * 4] = v;
            mx = fmaxf(mx, fmaxf(fmaxf(v.x, v.y), fmaxf(v.z, v.w)));
        }
        mx = fmaxf(mx, __shfl_xor(mx, 1));
        mx = fmaxf(mx, __shfl_xor(mx, 2));
        if (tq == 0) sRed[tr] = mx;
    }
    __syncthreads();
    if (t < 64) {
        float rm = sRed[t], M = rm;
#pragma unroll
        for (int off = 1; off < 64; off <<= 1) M = fmaxf(M, __shfl_xor(M, off));
        sRed[128 + t] = __expf(rm - M);
    }
    {
        float rmax = sRed[tr];
        float4* rp = (float4*)&sG[tr][tn0];
        float s = 0.f;
#pragma unroll
        for (int q2 = 0; q2 < 4; ++q2) {
            float4 v = rp[q2];
            float4 ev;
            ev.x = __expf(v.x - rmax); ev.y = __expf(v.y - rmax);
            ev.z = __expf(v.z - rmax); ev.w = __expf(v.w - rmax);
            s += ev.x + ev.y + ev.z + ev.w;
            rp[q2] = ev;
        }
        s += __shfl_xor(s, 1);
        s += __shfl_xor(s, 2);
        if (tq == 0) sRed[64 + tr] = 1.f / s;
    }
    __syncthreads();

    if (which == 0) {
        float rinv = sRed[64 + tr];
        const float4* rp = (const float4*)&sG[tr][tn0];
#pragma unroll
        for (int g2 = 0; g2 < 2; ++g2) {
            float4 v0 = rp[g2 * 2], v1 = rp[g2 * 2 + 1];
            s16x8 pk;
            pk[0] = (short)f2b(v0.x * rinv); pk[1] = (short)f2b(v0.y * rinv);
            pk[2] = (short)f2b(v0.z * rinv); pk[3] = (short)f2b(v0.w * rinv);
            pk[4] = (short)f2b(v1.x * rinv); pk[5] = (short)f2b(v1.y * rinv);
            pk[6] = (short)f2b(v1.z * rinv); pk[7] = (short)f2b(v1.w * rinv);
            *(s16x8*)&Gbf[tr][tn0 + g2 * 8] = pk;
        }
    } else {
        float cs = 0.f;
#pragma unroll
        for (int k = 0; k < 16; ++k) {
            int mm = tn0 + k;
            cs += sG[mm][tr] * sRed[128 + mm];
        }
        cs += __shfl_xor(cs, 1);
        cs += __shfl_xor(cs, 2);
        if (tq == 0) sRed[192 + tr] = 1.f / cs;
    }
    __syncthreads();
    if (which == 1) {
        float cinv = sRed[192 + tr];
#pragma unroll
        for (int g2 = 0; g2 < 2; ++g2) {
            s16x8 pk;
#pragma unroll
            for (int k = 0; k < 8; ++k) {
                int mm = tn0 + g2 * 8 + k;
                pk[k] = (short)f2b(sG[mm][tr] * sRed[128 + mm] * cinv);
            }
            *(s16x8*)&Gbf[tr][tn0 + g2 * 8] = pk;
        }
    }
    __syncthreads();

    const u16* lT = which ? xlT : ylT;
    const float* res = which ? y : x;
    int off = which ? 65536 : 0;
    int mcol = w * 16 + l15;
    f32x4 acc[8];
#pragma unroll
    for (int mt = 0; mt < 8; ++mt) acc[mt] = (f32x4)(0.f);
#pragma unroll
    for (int kt = 0; kt < 2; ++kt) {
        s16x8 bfr = *(const s16x8*)&Gbf[mcol][kt * 32 + q4 * 8];
#pragma unroll
        for (int mt = 0; mt < 8; ++mt) {
            s16x8 af = *(const s16x8*)(lT + (b * 128 + mt * 16 + l15) * 64 + kt * 32 + q4 * 8);
            acc[mt] = __builtin_amdgcn_mfma_f32_16x16x32_bf16(af, bfr, acc[mt], 0, 0, 0);
        }
    }
#pragma unroll
    for (int mt = 0; mt < 8; ++mt) {
        int i0 = mt * 16 + q4 * 4;
        f32x4 a = acc[mt];
#pragma unroll
        for (int r = 0; r < 4; ++r) {
            int ad = (b * 128 + i0 + r) * 64 + mcol;
            out[off + ad] = a[r] + res[ad];
        }
    }
}

extern "C" void kernel_launch(void* const* d_in, const int* in_sizes, int n_in,
                              void* d_out, int out_size, void* d_ws, size_t ws_size,
                              hipStream_t stream) {
    const float* x = (const float*)d_in[0];
    const float* y = (const float*)d_in[1];
    const float* m_bias = (const float*)d_in[2];
    const int* edge_mat = (const int*)d_in[3];
    const float* p_bias = (const float*)d_in[4];
    const int* path_mat = (const int*)d_in[5];
    const float* pre = (const float*)d_in[6];
    const float* xc1 = (const float*)d_in[7];
    const float* yc1 = (const float*)d_in[8];
    const float* xc2w = (const float*)d_in[9];
    const float* xc2b = (const float*)d_in[10];
    const float* yc2w = (const float*)d_in[11];
    const float* yc2b = (const float*)d_in[12];
    const float* pconv = (const float*)d_in[13];
    const float* econv = (const float*)d_in[14];
    const float* w1 = (const float*)d_in[15];
    const float* b1 = (const float*)d_in[16];
    const float* w2 = (const float*)d_in[17];
    const float* b2 = (const float*)d_in[18];
    const float* score_w = (const float*)d_in[19];
    const float* xlw = (const float*)d_in[20];
    const float* ylw = (const float*)d_in[21];
    const float* etab = (const float*)d_in[22];
    const float* ptab = (const float*)d_in[23];

    float* Xs = (float*)d_ws;               // 512 f
    float* Yo = Xs + 512;                   // 512 f
    float* g = Yo + 512;                    // 32768 f
    float* xfT = g + 32768;                 // 65536 f
    float* yfT = xfT + 65536;               // 65536 f
    u16* wA1 = (u16*)(yfT + 65536);         // 49152 u16
    u16* wA2 = wA1 + 49152;                 // 147456 u16
    u16* xfb = wA2 + 147456;                // 65536 u16
    u16* yfb = xfb + 65536;
    u16* xlT = yfb + 65536;
    u16* ylT = xlT + 65536;
    u16* preT = ylT + 65536;                // 4194304 u16 (8 MiB)
    u16* hT = preT + 4194304;               // 4194304 u16 (8 MiB)

    float* out = (float*)d_out;
    float* out_m2r = out + 131072;

    hipLaunchKernelGGL(k_prep, dim3(1312), dim3(256), 0, stream, w1, w2, wA1, wA2,
                       x, y, xc1, yc1, xc2w, xc2b, yc2w, yc2b, xlw, ylw,
                       xfb, yfb, xfT, yfT, xlT, ylT, Xs, Yo, pre, preT);
    hipLaunchKernelGGL(k_attnc, dim3(512), dim3(256), 0, stream, Xs, Yo, xfb, yfb, xfT, yfT,
                       path_mat, p_bias, ptab, pconv, preT, wA1, b1, hT);
    hipLaunchKernelGGL(k_conv2, dim3(512), dim3(256), 0, stream, hT, wA2, b2, score_w,
                       Xs, Yo, etab, econv, edge_mat, m_bias, out_m2r, g);
    hipLaunchKernelGGL(k_gout, dim3(16), dim3(256), 0, stream, g, xlT, ylT, x, y, out);
}